// Round 13
// baseline (1494.739 us; speedup 1.0000x reference)
//
#include <hip/hip_runtime.h>
#include <hip/hip_bf16.h>

// Problem constants
#define BB 32    // batch
#define TT 128   // T_E == T_D
#define HH 256   // hidden
#define G4 4     // blocks per batch for LSTM
#define UPB 64   // units per LSTM slice (256/4)
#define RPB 256  // gate rows per LSTM slice (4 gates * 64 units)

#define AGENT __HIP_MEMORY_SCOPE_AGENT
#define AL(p) __hip_atomic_load((p), __ATOMIC_RELAXED, AGENT)

__device__ __forceinline__ float rcp_f(float x) { return __builtin_amdgcn_rcpf(x); }
__device__ __forceinline__ float sigmoid_f(float x) {
    return rcp_f(1.f + __expf(-x));  // ~1e-7 rel err vs 7e-3 threshold
}
__device__ __forceinline__ float tanh_f(float x) {
    float e = __expf(2.f * x);
    return 1.f - 2.f * rcp_f(e + 1.f);
}

// ---------------------------------------------------------------------------
// LSTM + fused projections (R12 structure + conflict-free proj k-reads).
// grid = 128 (blk = g*32 + b); block = 512 = 8 waves.
// Waves 0-7: phase 1; wave 0: phase 2 (serial, publishes 8B mbox packet only);
// waves 1-3: ring poll; waves 4-7: e2/d2 row t-1 from double-buffered hbuf.
// Proj reads staggered idx=(i+2*kq)&15 -> quarter addresses hit bank groups
// {4i,4i+8,4i+16,4i+24}: conflict-free (R12's kq*64 offsets were 4-way).
// ---------------------------------------------------------------------------
__global__ __launch_bounds__(512, 2) void lstm_kernel(
    const float* __restrict__ seq,     // [B][128]
    const int* __restrict__ seq_m,     // [B]
    const float* __restrict__ target,  // [B][128]
    const float* __restrict__ Wih_e,   // [1024]
    const float* __restrict__ Whh_e,   // [1024][256]
    const float* __restrict__ bih_e, const float* __restrict__ bhh_e,
    const float* __restrict__ Wih_d, const float* __restrict__ Whh_d,
    const float* __restrict__ bih_d, const float* __restrict__ bhh_d,
    const float* __restrict__ We, const float* __restrict__ be,
    const float* __restrict__ Wd, const float* __restrict__ bd,
    float* __restrict__ e2,  // [B][128][256]
    float* __restrict__ d2,  // [B][128][256]
    unsigned long long* __restrict__ mbox,   // [2][B][256] tagged h packets
    unsigned long long* __restrict__ hsave)  // [B][256] tag-1 enc state @ last
{
    const int blk = blockIdx.x;
    const int b = blk & 31;   // batch
    const int g = blk >> 5;   // slice 0..3
    const int tid = threadIdx.x;
    const int row_local = tid >> 1;  // 0..255
    const int half = tid & 1;        // k-half
    const int gate = row_local >> 6; // 0..3 (i,f,g,o)
    const int u_local = row_local & 63;
    const int row_global = gate * HH + g * UPB + u_local;
    const int last = seq_m[b] - 1;
    // proj role (waves 4-7): s in [0,256); col g*64+(s>>2); k-quarter s&3
    const int s = tid - 256;
    const int pu = s >> 2;
    const int kq = s & 3;
    const int pcol = g * UPB + pu;

    __shared__ float hbuf[2][HH];   // double-buffered h (phase1 reads ^1)
    __shared__ float g_lds[RPB];
    __shared__ float x_lds[2 * TT];
    __shared__ float h_final[HH];   // boundary h vector (rows 127)

    for (int i = tid; i < TT; i += 512) {
        x_lds[i] = seq[b * TT + i];
        x_lds[TT + i] = target[b * TT + i];
    }

    float4 w[32];
    float bias_r, wih_r;
    auto loadw = [&](const float* Whh, const float* Wih,
                     const float* bih, const float* bhh) {
        const float4* wr = (const float4*)(Whh + row_global * HH + half * 128);
#pragma unroll
        for (int i = 0; i < 32; ++i) w[i] = wr[i];
        bias_r = bih[row_global] + bhh[row_global];
        wih_r = Wih[row_global];
    };
    loadw(Whh_e, Wih_e, bih_e, bhh_e);

    float4 pw[16];
    float pb = 0.f;
    auto loadp = [&](const float* W, const float* bias) {
        const float4* src = (const float4*)(W + pcol * HH + kq * 64);
#pragma unroll
        for (int i = 0; i < 16; ++i) pw[i] = src[i];
        pb = bias[pcol];
    };
    if (tid >= 256) loadp(We, be);

    // conflict-free staggered proj dot (bank groups {4i,4i+8,4i+16,4i+24})
    auto projdot = [&](const float* hsrc) -> float {
        const float4* hp = (const float4*)(hsrc + kq * 64);
        float pa = 0.f;
#pragma unroll
        for (int i = 0; i < 16; ++i) {
            const int idx = (i + 2 * kq) & 15;
            float4 hv = hp[idx];
            pa = fmaf(pw[idx].x, hv.x, pa);
            pa = fmaf(pw[idx].y, hv.y, pa);
            pa = fmaf(pw[idx].z, hv.z, pa);
            pa = fmaf(pw[idx].w, hv.w, pa);
        }
        pa += __shfl_xor(pa, 1);
        pa += __shfl_xor(pa, 2);  // 4 k-quarters combined
        return pa + pb;
    };

    if (tid < 64) {  // h(-1) = 0 lives in buffer 1
        ((float4*)hbuf[1])[tid] = make_float4(0.f, 0.f, 0.f, 0.f);
    }
    __syncthreads();

    float c = 0.f, c_saved = 0.f, h_saved = 0.f;

    for (int t = 0; t < 2 * TT; ++t) {
        const int phase = t >> 7;  // 0 = encoder, 1 = decoder
        const int tt = t & 127;
        const float x = x_lds[t];
        const int rb = (t & 1) ^ 1;  // buffer holding h(t-1)

        // ---- phase 1 (all 8 waves): gate-row dot over own 128-wide slice --
        const float4* h4 = ((const float4*)hbuf[rb]) + half * 32;
        float4 a4 = make_float4(0.f, 0.f, 0.f, 0.f);
#pragma unroll
        for (int i = 0; i < 32; ++i) {
            float4 hv = h4[i];
            a4.x = fmaf(w[i].x, hv.x, a4.x);
            a4.y = fmaf(w[i].y, hv.y, a4.y);
            a4.z = fmaf(w[i].z, hv.z, a4.z);
            a4.w = fmaf(w[i].w, hv.w, a4.w);
        }
        float acc = (a4.x + a4.y) + (a4.z + a4.w);
        acc += __shfl_xor(acc, 1);  // combine the two k-halves
        float gv = acc + bias_r + x * wih_r;  // bias/Wih folded off serial path
        if (half == 0) g_lds[row_local] = gv;
        __syncthreads();  // (A) gates visible; hbuf[t&1] free to write

        // ---- phase 2 (wave 0): minimal serial segment ----
        if (tid < 64) {
            float gi = g_lds[tid];
            float gf = g_lds[64 + tid];
            float gg = g_lds[128 + tid];
            float go = g_lds[192 + tid];
            float si = sigmoid_f(gi);
            float sf = sigmoid_f(gf);
            float tg = tanh_f(gg);
            float so = sigmoid_f(go);
            c = sf * c + si * tg;
            float h = so * tanh_f(c);
            const int ug = g * UPB + tid;
            // publish FIRST: the only VMEM op on wave 0's pre-barrier drain
            unsigned long long pkt =
                ((unsigned long long)(unsigned)(t + 1) << 32) | __float_as_uint(h);
            __hip_atomic_store(&mbox[(t & 1) * BB * HH + b * HH + ug], pkt,
                               __ATOMIC_RELAXED, AGENT);
            if (phase == 0 && tt == last) {
                c_saved = c;
                h_saved = h;
                unsigned long long spkt =
                    (1ull << 32) | (unsigned long long)__float_as_uint(h);
                __hip_atomic_store(&hsave[b * HH + ug], spkt, __ATOMIC_RELAXED, AGENT);
            }
            hbuf[t & 1][ug] = (t == TT - 1) ? h_saved : h;
        }

        // ---- phase 3 (waves 1..3): ring poll of partners' tagged h ----
        if (tid >= 64 && tid < 256) {
            const int p = (g + (tid >> 6)) & 3;  // partner slice 1..3 away
            const int lane = tid & 63;
            const int ppu = p * UPB + lane;
            unsigned long long* src;
            unsigned want;
            if (t == TT - 1) {
                src = &hsave[b * HH + ppu];
                want = 1u;
            } else {
                src = &mbox[(t & 1) * BB * HH + b * HH + ppu];
                want = (unsigned)(t + 1);
            }
            unsigned long long pv;
            {
                unsigned long long r0 = AL(src);
                unsigned long long r1 = AL(src);
                unsigned long long r2 = AL(src);
                unsigned long long r3 = AL(src);
                for (;;) {
                    if ((unsigned)(r0 >> 32) == want) { pv = r0; break; }
                    r0 = AL(src);
                    if ((unsigned)(r1 >> 32) == want) { pv = r1; break; }
                    r1 = AL(src);
                    if ((unsigned)(r2 >> 32) == want) { pv = r2; break; }
                    r2 = AL(src);
                    if ((unsigned)(r3 >> 32) == want) { pv = r3; break; }
                    r3 = AL(src);
                }
            }
            hbuf[t & 1][ppu] = __uint_as_float((unsigned)pv);
        }

        // ---- proj (waves 4..7): e2/d2 row t-1, hidden in the poll window --
        if (tid >= 256 && t >= 1) {
            const float* hsrc = (t == TT) ? h_final : hbuf[rb];
            float pv = projdot(hsrc);
            if (kq == 0) {
                if (t <= TT)
                    e2[(b * TT + (t - 1)) * HH + pcol] = pv;
                else
                    d2[(b * TT + (t - 1 - TT)) * HH + pcol] = pv;
            }
        }
        // at the enc boundary, recover full h(TT-1) (tag TT) into h_final
        if (tid >= 256 && t == TT - 1) {
            unsigned long long* src = &mbox[((TT - 1) & 1) * BB * HH + b * HH + s];
            const unsigned want = (unsigned)TT;
            unsigned long long r0 = AL(src);
            unsigned long long r1 = AL(src);
            unsigned long long pv;
            for (;;) {
                if ((unsigned)(r0 >> 32) == want) { pv = r0; break; }
                r0 = AL(src);
                if ((unsigned)(r1 >> 32) == want) { pv = r1; break; }
                r1 = AL(src);
            }
            h_final[s] = __uint_as_float((unsigned)pv);
        }
        if (tid >= 256 && t == TT) loadp(Wd, bd);

        __syncthreads();  // (B) hbuf[t&1] complete for next step

        if (t == TT - 1) {  // encoder -> decoder transition
            loadw(Whh_d, Wih_d, bih_d, bhh_d);
            c = c_saved;
        }
    }

    // ---- post-loop: d2 row TT-1 from h(2TT-1) (tag 2TT) ----
    if (tid >= 256) {
        unsigned long long* src = &mbox[((2 * TT - 1) & 1) * BB * HH + b * HH + s];
        const unsigned want = (unsigned)(2 * TT);
        unsigned long long r0 = AL(src);
        unsigned long long r1 = AL(src);
        unsigned long long pv;
        for (;;) {
            if ((unsigned)(r0 >> 32) == want) { pv = r0; break; }
            r0 = AL(src);
            if ((unsigned)(r1 >> 32) == want) { pv = r1; break; }
            r1 = AL(src);
        }
        h_final[s] = __uint_as_float((unsigned)pv);
    }
    __syncthreads();
    if (tid >= 256) {
        float pv = projdot(h_final);
        if (kq == 0) d2[(b * TT + (TT - 1)) * HH + pcol] = pv;
    }
}

// ---------------------------------------------------------------------------
// Attention scores: p = tanh(e2_j + d2_i) . v  for a 32x32 (i,j) tile.
// grid = 512 = b(32) x it(4) x jt(4); block = 256 (ig 0..7 x jl 0..31),
// 4x i-register-blocked; single stage (no jc loop), results straight to p_ws.
// 512 blocks -> all 256 CUs busy (R12's 128-block attn used half the chip).
// ---------------------------------------------------------------------------
#define EPAD 260  // float4-aligned LDS row stride
__global__ __launch_bounds__(256) void attn_p_kernel(
    const float* __restrict__ e2, const float* __restrict__ d2,
    const float* __restrict__ vv, float* __restrict__ p_ws) {
    __shared__ float e2c[32][EPAD];
    __shared__ float d2t[32][EPAD];
    __shared__ float v_lds[HH];

    const int blk = blockIdx.x;
    const int b = blk >> 4;
    const int i0 = ((blk >> 2) & 3) * 32;
    const int j0 = (blk & 3) * 32;
    const int tid = threadIdx.x;
    const int jl = tid & 31, ig = tid >> 5;

    if (tid < 64) *(float4*)&v_lds[tid * 4] = ((const float4*)vv)[tid];
    for (int idx = tid; idx < 32 * 64; idx += 256) {
        int r = idx >> 6, q = idx & 63;
        *(float4*)&d2t[r][q * 4] = ((const float4*)(d2 + (b * TT + i0 + r) * HH))[q];
        *(float4*)&e2c[r][q * 4] = ((const float4*)(e2 + (b * TT + j0 + r) * HH))[q];
    }
    __syncthreads();

    float a0 = 0.f, a1 = 0.f, a2 = 0.f, a3 = 0.f;
    for (int h = 0; h < HH; h += 4) {
        float4 ev = *(const float4*)&e2c[jl][h];
        float4 vx = *(const float4*)&v_lds[h];
        float4 d0 = *(const float4*)&d2t[ig * 4 + 0][h];
        float4 d1 = *(const float4*)&d2t[ig * 4 + 1][h];
        float4 d2v = *(const float4*)&d2t[ig * 4 + 2][h];
        float4 d3 = *(const float4*)&d2t[ig * 4 + 3][h];
        a0 = fmaf(tanh_f(ev.x + d0.x), vx.x, a0);
        a0 = fmaf(tanh_f(ev.y + d0.y), vx.y, a0);
        a0 = fmaf(tanh_f(ev.z + d0.z), vx.z, a0);
        a0 = fmaf(tanh_f(ev.w + d0.w), vx.w, a0);
        a1 = fmaf(tanh_f(ev.x + d1.x), vx.x, a1);
        a1 = fmaf(tanh_f(ev.y + d1.y), vx.y, a1);
        a1 = fmaf(tanh_f(ev.z + d1.z), vx.z, a1);
        a1 = fmaf(tanh_f(ev.w + d1.w), vx.w, a1);
        a2 = fmaf(tanh_f(ev.x + d2v.x), vx.x, a2);
        a2 = fmaf(tanh_f(ev.y + d2v.y), vx.y, a2);
        a2 = fmaf(tanh_f(ev.z + d2v.z), vx.z, a2);
        a2 = fmaf(tanh_f(ev.w + d2v.w), vx.w, a2);
        a3 = fmaf(tanh_f(ev.x + d3.x), vx.x, a3);
        a3 = fmaf(tanh_f(ev.y + d3.y), vx.y, a3);
        a3 = fmaf(tanh_f(ev.z + d3.z), vx.z, a3);
        a3 = fmaf(tanh_f(ev.w + d3.w), vx.w, a3);
    }
    float* pr = p_ws + (b * TT + i0 + ig * 4) * TT + j0 + jl;
    pr[0 * TT] = a0;
    pr[1 * TT] = a1;
    pr[2 * TT] = a2;
    pr[3 * TT] = a3;
}

// ---------------------------------------------------------------------------
// Softmax over j with mask (memory-bound finisher).
// grid = 256 = b(32) x 8 row-tiles (16 rows); block = 256 (16 rows x 16 lanes).
// ---------------------------------------------------------------------------
__global__ __launch_bounds__(256) void attn_sm_kernel(
    const float* __restrict__ p_ws, const float* __restrict__ seq,
    float* __restrict__ out) {
    const int blk = blockIdx.x;
    const int b = blk >> 3;
    const int r0 = (blk & 7) * 16;
    const int tid = threadIdx.x;
    const int r = tid >> 4, l16 = tid & 15;
    const int row = (b * TT + r0 + r) * TT;

    float xr[8];
    float m = -1e30f;
#pragma unroll
    for (int k = 0; k < 8; ++k) {
        const int j = l16 + 16 * k;
        float x = p_ws[row + j];
        float sv = (j == 0) ? 0.1f : seq[b * TT + j];
        if (sv == 0.f) x -= 1000.f;
        xr[k] = x;
        m = fmaxf(m, x);
    }
#pragma unroll
    for (int o = 8; o >= 1; o >>= 1) m = fmaxf(m, __shfl_xor(m, o));
    float s = 0.f;
#pragma unroll
    for (int k = 0; k < 8; ++k) {
        xr[k] = __expf(xr[k] - m);
        s += xr[k];
    }
#pragma unroll
    for (int o = 8; o >= 1; o >>= 1) s += __shfl_xor(s, o);
    float inv = rcp_f(s);
#pragma unroll
    for (int k = 0; k < 8; ++k) out[row + l16 + 16 * k] = xr[k] * inv;
}

// ---------------------------------------------------------------------------
extern "C" void kernel_launch(void* const* d_in, const int* in_sizes, int n_in,
                              void* d_out, int out_size, void* d_ws, size_t ws_size,
                              hipStream_t stream) {
    const float* seq = (const float*)d_in[0];
    const int* seq_m = (const int*)d_in[1];
    const float* target = (const float*)d_in[2];
    const float* Wih_e = (const float*)d_in[3];
    const float* Whh_e = (const float*)d_in[4];
    const float* bih_e = (const float*)d_in[5];
    const float* bhh_e = (const float*)d_in[6];
    const float* Wih_d = (const float*)d_in[7];
    const float* Whh_d = (const float*)d_in[8];
    const float* bih_d = (const float*)d_in[9];
    const float* bhh_d = (const float*)d_in[10];
    const float* We = (const float*)d_in[11];
    const float* be = (const float*)d_in[12];
    const float* Wd = (const float*)d_in[13];
    const float* bd = (const float*)d_in[14];
    const float* vv = (const float*)d_in[15];

    float* ws = (float*)d_ws;
    const size_t SZ_ED = (size_t)BB * TT * HH;  // 1,048,576 floats
    float* e2 = ws;
    float* d2 = e2 + SZ_ED;
    float* p_ws = d2 + SZ_ED;                               // [B][128][128]
    unsigned long long* mbox =
        (unsigned long long*)(p_ws + (size_t)BB * TT * TT);  // [2][B][H]
    unsigned long long* hsave = mbox + 2 * BB * HH;          // [B][H]

    const size_t needed = (2 * SZ_ED + (size_t)BB * TT * TT) * sizeof(float) +
                          3 * BB * HH * sizeof(unsigned long long);
    if (ws_size < needed) return;

    hipMemsetAsync(mbox, 0, 3 * BB * HH * sizeof(unsigned long long), stream);
    lstm_kernel<<<BB * G4, 512, 0, stream>>>(seq, seq_m, target, Wih_e, Whh_e, bih_e,
                                             bhh_e, Wih_d, Whh_d, bih_d, bhh_d, We,
                                             be, Wd, bd, e2, d2, mbox, hsave);
    attn_p_kernel<<<512, 256, 0, stream>>>(e2, d2, vv, p_ws);
    attn_sm_kernel<<<256, 256, 0, stream>>>(p_ws, seq, (float*)d_out);
}

// Round 14
// 688.795 us; speedup vs baseline: 2.1701x; 2.1701x over previous
//
#include <hip/hip_runtime.h>
#include <hip/hip_bf16.h>

// Problem constants
#define BB 32    // batch
#define TT 128   // T_E == T_D
#define HH 256   // hidden
#define G4 4     // blocks per batch for LSTM
#define UPB 64   // units per LSTM slice (256/4)
#define RPB 256  // gate rows per LSTM slice (4 gates * 64 units)

#define AGENT __HIP_MEMORY_SCOPE_AGENT
#define AL(p) __hip_atomic_load((p), __ATOMIC_RELAXED, AGENT)

__device__ __forceinline__ float rcp_f(float x) { return __builtin_amdgcn_rcpf(x); }
__device__ __forceinline__ float sigmoid_f(float x) {
    return rcp_f(1.f + __expf(-x));  // ~1e-7 rel err vs 7e-3 threshold
}
__device__ __forceinline__ float tanh_f(float x) {
    float e = __expf(2.f * x);
    return 1.f - 2.f * rcp_f(e + 1.f);
}

// ---------------------------------------------------------------------------
// LSTM + fused projections.
// grid = 128 (blk = g*32 + b); block = 512 = 8 waves.
// Waves 0-7: phase 1; wave 0: phase 2 (serial, publishes 8B mbox packet only);
// waves 1-3: ring poll; waves 4-7: e2/d2 row t-1 from double-buffered hbuf.
// Proj stagger is applied at LOAD time: pw[i] (static register index) holds
// W row element (i+2*kq)&15, and the LDS read uses the rotated ADDRESS
// hp[(i+2*kq)&15]. R13's pw[idx] with runtime idx demoted pw[] to scratch
// (+12MB WRITE_SIZE, 3x lstm regression). Dynamic LDS/global ADDRESSES are
// fine; dynamic REGISTER indices are not.
// ---------------------------------------------------------------------------
__global__ __launch_bounds__(512, 2) void lstm_kernel(
    const float* __restrict__ seq,     // [B][128]
    const int* __restrict__ seq_m,     // [B]
    const float* __restrict__ target,  // [B][128]
    const float* __restrict__ Wih_e,   // [1024]
    const float* __restrict__ Whh_e,   // [1024][256]
    const float* __restrict__ bih_e, const float* __restrict__ bhh_e,
    const float* __restrict__ Wih_d, const float* __restrict__ Whh_d,
    const float* __restrict__ bih_d, const float* __restrict__ bhh_d,
    const float* __restrict__ We, const float* __restrict__ be,
    const float* __restrict__ Wd, const float* __restrict__ bd,
    float* __restrict__ e2,  // [B][128][256]
    float* __restrict__ d2,  // [B][128][256]
    unsigned long long* __restrict__ mbox,   // [2][B][256] tagged h packets
    unsigned long long* __restrict__ hsave)  // [B][256] tag-1 enc state @ last
{
    const int blk = blockIdx.x;
    const int b = blk & 31;   // batch
    const int g = blk >> 5;   // slice 0..3
    const int tid = threadIdx.x;
    const int row_local = tid >> 1;  // 0..255
    const int half = tid & 1;        // k-half
    const int gate = row_local >> 6; // 0..3 (i,f,g,o)
    const int u_local = row_local & 63;
    const int row_global = gate * HH + g * UPB + u_local;
    const int last = seq_m[b] - 1;
    // proj role (waves 4-7): s in [0,256); col g*64+(s>>2); k-quarter s&3
    const int s = tid - 256;
    const int pu = s >> 2;
    const int kq = s & 3;
    const int pcol = g * UPB + pu;
    const int rot = 2 * kq;  // stagger amount

    __shared__ float hbuf[2][HH];   // double-buffered h (phase1 reads ^1)
    __shared__ float g_lds[RPB];
    __shared__ float x_lds[2 * TT];
    __shared__ float h_final[HH];   // boundary h vector (rows 127)

    for (int i = tid; i < TT; i += 512) {
        x_lds[i] = seq[b * TT + i];
        x_lds[TT + i] = target[b * TT + i];
    }

    float4 w[32];
    float bias_r, wih_r;
    auto loadw = [&](const float* Whh, const float* Wih,
                     const float* bih, const float* bhh) {
        const float4* wr = (const float4*)(Whh + row_global * HH + half * 128);
#pragma unroll
        for (int i = 0; i < 32; ++i) w[i] = wr[i];
        bias_r = bih[row_global] + bhh[row_global];
        wih_r = Wih[row_global];
    };
    loadw(Whh_e, Wih_e, bih_e, bhh_e);

    // proj weights loaded in ROTATED order: pw[i] = W element (i+rot)&15.
    float4 pw[16];
    float pb = 0.f;
    auto loadp = [&](const float* W, const float* bias) {
        const float4* src = (const float4*)(W + pcol * HH + kq * 64);
#pragma unroll
        for (int i = 0; i < 16; ++i) pw[i] = src[(i + rot) & 15];
        pb = bias[pcol];
    };
    if (tid >= 256) loadp(We, be);

    // proj dot: static register index pw[i], rotated LDS ADDRESS hp[(i+rot)&15]
    // -> quarter addresses hit bank groups {4i, 4i+8, 4i+16, 4i+24}: no
    // conflicts, and no scratch demotion.
    auto projdot = [&](const float* hsrc) -> float {
        const float4* hp = (const float4*)(hsrc + kq * 64);
        float pa = 0.f;
#pragma unroll
        for (int i = 0; i < 16; ++i) {
            float4 hv = hp[(i + rot) & 15];
            pa = fmaf(pw[i].x, hv.x, pa);
            pa = fmaf(pw[i].y, hv.y, pa);
            pa = fmaf(pw[i].z, hv.z, pa);
            pa = fmaf(pw[i].w, hv.w, pa);
        }
        pa += __shfl_xor(pa, 1);
        pa += __shfl_xor(pa, 2);  // 4 k-quarters combined
        return pa + pb;
    };

    if (tid < 64) {  // h(-1) = 0 lives in buffer 1
        ((float4*)hbuf[1])[tid] = make_float4(0.f, 0.f, 0.f, 0.f);
    }
    __syncthreads();

    float c = 0.f, c_saved = 0.f, h_saved = 0.f;

    for (int t = 0; t < 2 * TT; ++t) {
        const int phase = t >> 7;  // 0 = encoder, 1 = decoder
        const int tt = t & 127;
        const float x = x_lds[t];
        const int rb = (t & 1) ^ 1;  // buffer holding h(t-1)

        // ---- phase 1 (all 8 waves): gate-row dot over own 128-wide slice --
        const float4* h4 = ((const float4*)hbuf[rb]) + half * 32;
        float4 a4 = make_float4(0.f, 0.f, 0.f, 0.f);
#pragma unroll
        for (int i = 0; i < 32; ++i) {
            float4 hv = h4[i];
            a4.x = fmaf(w[i].x, hv.x, a4.x);
            a4.y = fmaf(w[i].y, hv.y, a4.y);
            a4.z = fmaf(w[i].z, hv.z, a4.z);
            a4.w = fmaf(w[i].w, hv.w, a4.w);
        }
        float acc = (a4.x + a4.y) + (a4.z + a4.w);
        acc += __shfl_xor(acc, 1);  // combine the two k-halves
        float gv = acc + bias_r + x * wih_r;  // bias/Wih folded off serial path
        if (half == 0) g_lds[row_local] = gv;
        __syncthreads();  // (A) gates visible; hbuf[t&1] free to write

        // ---- phase 2 (wave 0): minimal serial segment ----
        if (tid < 64) {
            float gi = g_lds[tid];
            float gf = g_lds[64 + tid];
            float gg = g_lds[128 + tid];
            float go = g_lds[192 + tid];
            float si = sigmoid_f(gi);
            float sf = sigmoid_f(gf);
            float tg = tanh_f(gg);
            float so = sigmoid_f(go);
            c = sf * c + si * tg;
            float h = so * tanh_f(c);
            const int ug = g * UPB + tid;
            // publish FIRST: the only VMEM op on wave 0's pre-barrier drain
            unsigned long long pkt =
                ((unsigned long long)(unsigned)(t + 1) << 32) | __float_as_uint(h);
            __hip_atomic_store(&mbox[(t & 1) * BB * HH + b * HH + ug], pkt,
                               __ATOMIC_RELAXED, AGENT);
            if (phase == 0 && tt == last) {
                c_saved = c;
                h_saved = h;
                unsigned long long spkt =
                    (1ull << 32) | (unsigned long long)__float_as_uint(h);
                __hip_atomic_store(&hsave[b * HH + ug], spkt, __ATOMIC_RELAXED, AGENT);
            }
            hbuf[t & 1][ug] = (t == TT - 1) ? h_saved : h;
        }

        // ---- phase 3 (waves 1..3): ring poll of partners' tagged h ----
        if (tid >= 64 && tid < 256) {
            const int p = (g + (tid >> 6)) & 3;  // partner slice 1..3 away
            const int lane = tid & 63;
            const int ppu = p * UPB + lane;
            unsigned long long* src;
            unsigned want;
            if (t == TT - 1) {
                src = &hsave[b * HH + ppu];
                want = 1u;
            } else {
                src = &mbox[(t & 1) * BB * HH + b * HH + ppu];
                want = (unsigned)(t + 1);
            }
            unsigned long long pv;
            {
                unsigned long long r0 = AL(src);
                unsigned long long r1 = AL(src);
                unsigned long long r2 = AL(src);
                unsigned long long r3 = AL(src);
                for (;;) {
                    if ((unsigned)(r0 >> 32) == want) { pv = r0; break; }
                    r0 = AL(src);
                    if ((unsigned)(r1 >> 32) == want) { pv = r1; break; }
                    r1 = AL(src);
                    if ((unsigned)(r2 >> 32) == want) { pv = r2; break; }
                    r2 = AL(src);
                    if ((unsigned)(r3 >> 32) == want) { pv = r3; break; }
                    r3 = AL(src);
                }
            }
            hbuf[t & 1][ppu] = __uint_as_float((unsigned)pv);
        }

        // ---- proj (waves 4..7): e2/d2 row t-1, hidden in the poll window --
        if (tid >= 256 && t >= 1) {
            const float* hsrc = (t == TT) ? h_final : hbuf[rb];
            float pv = projdot(hsrc);
            if (kq == 0) {
                if (t <= TT)
                    e2[(b * TT + (t - 1)) * HH + pcol] = pv;
                else
                    d2[(b * TT + (t - 1 - TT)) * HH + pcol] = pv;
            }
        }
        // at the enc boundary, recover full h(TT-1) (tag TT) into h_final
        if (tid >= 256 && t == TT - 1) {
            unsigned long long* src = &mbox[((TT - 1) & 1) * BB * HH + b * HH + s];
            const unsigned want = (unsigned)TT;
            unsigned long long r0 = AL(src);
            unsigned long long r1 = AL(src);
            unsigned long long pv;
            for (;;) {
                if ((unsigned)(r0 >> 32) == want) { pv = r0; break; }
                r0 = AL(src);
                if ((unsigned)(r1 >> 32) == want) { pv = r1; break; }
                r1 = AL(src);
            }
            h_final[s] = __uint_as_float((unsigned)pv);
        }
        if (tid >= 256 && t == TT) loadp(Wd, bd);

        __syncthreads();  // (B) hbuf[t&1] complete for next step

        if (t == TT - 1) {  // encoder -> decoder transition
            loadw(Whh_d, Wih_d, bih_d, bhh_d);
            c = c_saved;
        }
    }

    // ---- post-loop: d2 row TT-1 from h(2TT-1) (tag 2TT) ----
    if (tid >= 256) {
        unsigned long long* src = &mbox[((2 * TT - 1) & 1) * BB * HH + b * HH + s];
        const unsigned want = (unsigned)(2 * TT);
        unsigned long long r0 = AL(src);
        unsigned long long r1 = AL(src);
        unsigned long long pv;
        for (;;) {
            if ((unsigned)(r0 >> 32) == want) { pv = r0; break; }
            r0 = AL(src);
            if ((unsigned)(r1 >> 32) == want) { pv = r1; break; }
            r1 = AL(src);
        }
        h_final[s] = __uint_as_float((unsigned)pv);
    }
    __syncthreads();
    if (tid >= 256) {
        float pv = projdot(h_final);
        if (kq == 0) d2[(b * TT + (TT - 1)) * HH + pcol] = pv;
    }
}

// ---------------------------------------------------------------------------
// Attention scores: p = tanh(e2_j + d2_i) . v  for a 32x32 (i,j) tile.
// grid = 512 = b(32) x it(4) x jt(4); block = 256; 4x i-register-blocked.
// ---------------------------------------------------------------------------
#define EPAD 260  // float4-aligned LDS row stride
__global__ __launch_bounds__(256) void attn_p_kernel(
    const float* __restrict__ e2, const float* __restrict__ d2,
    const float* __restrict__ vv, float* __restrict__ p_ws) {
    __shared__ float e2c[32][EPAD];
    __shared__ float d2t[32][EPAD];
    __shared__ float v_lds[HH];

    const int blk = blockIdx.x;
    const int b = blk >> 4;
    const int i0 = ((blk >> 2) & 3) * 32;
    const int j0 = (blk & 3) * 32;
    const int tid = threadIdx.x;
    const int jl = tid & 31, ig = tid >> 5;

    if (tid < 64) *(float4*)&v_lds[tid * 4] = ((const float4*)vv)[tid];
    for (int idx = tid; idx < 32 * 64; idx += 256) {
        int r = idx >> 6, q = idx & 63;
        *(float4*)&d2t[r][q * 4] = ((const float4*)(d2 + (b * TT + i0 + r) * HH))[q];
        *(float4*)&e2c[r][q * 4] = ((const float4*)(e2 + (b * TT + j0 + r) * HH))[q];
    }
    __syncthreads();

    float a0 = 0.f, a1 = 0.f, a2 = 0.f, a3 = 0.f;
    for (int h = 0; h < HH; h += 4) {
        float4 ev = *(const float4*)&e2c[jl][h];
        float4 vx = *(const float4*)&v_lds[h];
        float4 d0 = *(const float4*)&d2t[ig * 4 + 0][h];
        float4 d1 = *(const float4*)&d2t[ig * 4 + 1][h];
        float4 d2v = *(const float4*)&d2t[ig * 4 + 2][h];
        float4 d3 = *(const float4*)&d2t[ig * 4 + 3][h];
        a0 = fmaf(tanh_f(ev.x + d0.x), vx.x, a0);
        a0 = fmaf(tanh_f(ev.y + d0.y), vx.y, a0);
        a0 = fmaf(tanh_f(ev.z + d0.z), vx.z, a0);
        a0 = fmaf(tanh_f(ev.w + d0.w), vx.w, a0);
        a1 = fmaf(tanh_f(ev.x + d1.x), vx.x, a1);
        a1 = fmaf(tanh_f(ev.y + d1.y), vx.y, a1);
        a1 = fmaf(tanh_f(ev.z + d1.z), vx.z, a1);
        a1 = fmaf(tanh_f(ev.w + d1.w), vx.w, a1);
        a2 = fmaf(tanh_f(ev.x + d2v.x), vx.x, a2);
        a2 = fmaf(tanh_f(ev.y + d2v.y), vx.y, a2);
        a2 = fmaf(tanh_f(ev.z + d2v.z), vx.z, a2);
        a2 = fmaf(tanh_f(ev.w + d2v.w), vx.w, a2);
        a3 = fmaf(tanh_f(ev.x + d3.x), vx.x, a3);
        a3 = fmaf(tanh_f(ev.y + d3.y), vx.y, a3);
        a3 = fmaf(tanh_f(ev.z + d3.z), vx.z, a3);
        a3 = fmaf(tanh_f(ev.w + d3.w), vx.w, a3);
    }
    float* pr = p_ws + (b * TT + i0 + ig * 4) * TT + j0 + jl;
    pr[0 * TT] = a0;
    pr[1 * TT] = a1;
    pr[2 * TT] = a2;
    pr[3 * TT] = a3;
}

// ---------------------------------------------------------------------------
// Softmax over j with mask (memory-bound finisher).
// grid = 256 = b(32) x 8 row-tiles (16 rows); block = 256 (16 rows x 16 lanes).
// ---------------------------------------------------------------------------
__global__ __launch_bounds__(256) void attn_sm_kernel(
    const float* __restrict__ p_ws, const float* __restrict__ seq,
    float* __restrict__ out) {
    const int blk = blockIdx.x;
    const int b = blk >> 3;
    const int r0 = (blk & 7) * 16;
    const int tid = threadIdx.x;
    const int r = tid >> 4, l16 = tid & 15;
    const int row = (b * TT + r0 + r) * TT;

    float xr[8];
    float m = -1e30f;
#pragma unroll
    for (int k = 0; k < 8; ++k) {
        const int j = l16 + 16 * k;
        float x = p_ws[row + j];
        float sv = (j == 0) ? 0.1f : seq[b * TT + j];
        if (sv == 0.f) x -= 1000.f;
        xr[k] = x;
        m = fmaxf(m, x);
    }
#pragma unroll
    for (int o = 8; o >= 1; o >>= 1) m = fmaxf(m, __shfl_xor(m, o));
    float s = 0.f;
#pragma unroll
    for (int k = 0; k < 8; ++k) {
        xr[k] = __expf(xr[k] - m);
        s += xr[k];
    }
#pragma unroll
    for (int o = 8; o >= 1; o >>= 1) s += __shfl_xor(s, o);
    float inv = rcp_f(s);
#pragma unroll
    for (int k = 0; k < 8; ++k) out[row + l16 + 16 * k] = xr[k] * inv;
}

// ---------------------------------------------------------------------------
extern "C" void kernel_launch(void* const* d_in, const int* in_sizes, int n_in,
                              void* d_out, int out_size, void* d_ws, size_t ws_size,
                              hipStream_t stream) {
    const float* seq = (const float*)d_in[0];
    const int* seq_m = (const int*)d_in[1];
    const float* target = (const float*)d_in[2];
    const float* Wih_e = (const float*)d_in[3];
    const float* Whh_e = (const float*)d_in[4];
    const float* bih_e = (const float*)d_in[5];
    const float* bhh_e = (const float*)d_in[6];
    const float* Wih_d = (const float*)d_in[7];
    const float* Whh_d = (const float*)d_in[8];
    const float* bih_d = (const float*)d_in[9];
    const float* bhh_d = (const float*)d_in[10];
    const float* We = (const float*)d_in[11];
    const float* be = (const float*)d_in[12];
    const float* Wd = (const float*)d_in[13];
    const float* bd = (const float*)d_in[14];
    const float* vv = (const float*)d_in[15];

    float* ws = (float*)d_ws;
    const size_t SZ_ED = (size_t)BB * TT * HH;  // 1,048,576 floats
    float* e2 = ws;
    float* d2 = e2 + SZ_ED;
    float* p_ws = d2 + SZ_ED;                               // [B][128][128]
    unsigned long long* mbox =
        (unsigned long long*)(p_ws + (size_t)BB * TT * TT);  // [2][B][H]
    unsigned long long* hsave = mbox + 2 * BB * HH;          // [B][H]

    const size_t needed = (2 * SZ_ED + (size_t)BB * TT * TT) * sizeof(float) +
                          3 * BB * HH * sizeof(unsigned long long);
    if (ws_size < needed) return;

    hipMemsetAsync(mbox, 0, 3 * BB * HH * sizeof(unsigned long long), stream);
    lstm_kernel<<<BB * G4, 512, 0, stream>>>(seq, seq_m, target, Wih_e, Whh_e, bih_e,
                                             bhh_e, Wih_d, Whh_d, bih_d, bhh_d, We,
                                             be, Wd, bd, e2, d2, mbox, hsave);
    attn_p_kernel<<<512, 256, 0, stream>>>(e2, d2, vv, p_ws);
    attn_sm_kernel<<<256, 256, 0, stream>>>(p_ws, seq, (float*)d_out);
}

// Round 15
// 601.380 us; speedup vs baseline: 2.4855x; 1.1454x over previous
//
#include <hip/hip_runtime.h>
#include <hip/hip_bf16.h>

// Problem constants
#define BB 32    // batch
#define TT 128   // T_E == T_D
#define HH 256   // hidden
#define G4 4     // blocks per batch for LSTM
#define UPB 64   // units per LSTM slice (256/4)
#define RPB 256  // gate rows per LSTM slice (4 gates * 64 units)

#define AGENT __HIP_MEMORY_SCOPE_AGENT
#define AL(p) __hip_atomic_load((p), __ATOMIC_RELAXED, AGENT)

__device__ __forceinline__ float rcp_f(float x) { return __builtin_amdgcn_rcpf(x); }
__device__ __forceinline__ float sigmoid_f(float x) {
    return rcp_f(1.f + __expf(-x));  // ~1e-7 rel err vs 7e-3 threshold
}
__device__ __forceinline__ float tanh_f(float x) {
    float e = __expf(2.f * x);
    return 1.f - 2.f * rcp_f(e + 1.f);
}

// ---------------------------------------------------------------------------
// LSTM + fused projections — EXACT R12 structure (best measured: 545us).
// grid = 128 (blk = g*32 + b); block = 512 = 8 waves.
// Waves 0-7: phase 1; wave 0: phase 2 (serial, publishes 8B mbox packet only);
// waves 1-3: ring poll; waves 4-7: e2/d2 row t-1 from double-buffered hbuf.
// Proj reads are PLAIN hp[i] (compile-time offsets). Measured ledger:
//   R12 plain (4-way-conflicted): lstm 545us   <- best
//   R13 pw[runtime idx]: scratch demotion, 1449us
//   R14 rotated address: conflict-free but +addr-VALU in slot, 645us
// Conflicts are absorbed by slot slack; extra VALU is not. Do not "fix".
// ---------------------------------------------------------------------------
__global__ __launch_bounds__(512, 2) void lstm_kernel(
    const float* __restrict__ seq,     // [B][128]
    const int* __restrict__ seq_m,     // [B]
    const float* __restrict__ target,  // [B][128]
    const float* __restrict__ Wih_e,   // [1024]
    const float* __restrict__ Whh_e,   // [1024][256]
    const float* __restrict__ bih_e, const float* __restrict__ bhh_e,
    const float* __restrict__ Wih_d, const float* __restrict__ Whh_d,
    const float* __restrict__ bih_d, const float* __restrict__ bhh_d,
    const float* __restrict__ We, const float* __restrict__ be,
    const float* __restrict__ Wd, const float* __restrict__ bd,
    float* __restrict__ e2,  // [B][128][256]
    float* __restrict__ d2,  // [B][128][256]
    unsigned long long* __restrict__ mbox,   // [2][B][256] tagged h packets
    unsigned long long* __restrict__ hsave)  // [B][256] tag-1 enc state @ last
{
    const int blk = blockIdx.x;
    const int b = blk & 31;   // batch
    const int g = blk >> 5;   // slice 0..3
    const int tid = threadIdx.x;
    const int row_local = tid >> 1;  // 0..255
    const int half = tid & 1;        // k-half
    const int gate = row_local >> 6; // 0..3 (i,f,g,o)
    const int u_local = row_local & 63;
    const int row_global = gate * HH + g * UPB + u_local;
    const int last = seq_m[b] - 1;
    // proj role (waves 4-7): s in [0,256); col g*64+(s>>2); k-quarter s&3
    const int s = tid - 256;
    const int pu = s >> 2;
    const int kq = s & 3;
    const int pcol = g * UPB + pu;

    __shared__ float hbuf[2][HH];   // double-buffered h (phase1 reads ^1)
    __shared__ float g_lds[RPB];
    __shared__ float x_lds[2 * TT];
    __shared__ float h_final[HH];   // boundary h vector (rows 127)

    for (int i = tid; i < TT; i += 512) {
        x_lds[i] = seq[b * TT + i];
        x_lds[TT + i] = target[b * TT + i];
    }

    float4 w[32];
    float bias_r, wih_r;
    auto loadw = [&](const float* Whh, const float* Wih,
                     const float* bih, const float* bhh) {
        const float4* wr = (const float4*)(Whh + row_global * HH + half * 128);
#pragma unroll
        for (int i = 0; i < 32; ++i) w[i] = wr[i];
        bias_r = bih[row_global] + bhh[row_global];
        wih_r = Wih[row_global];
    };
    loadw(Whh_e, Wih_e, bih_e, bhh_e);

    float4 pw[16];
    float pb = 0.f;
    auto loadp = [&](const float* W, const float* bias) {
        const float4* src = (const float4*)(W + pcol * HH + kq * 64);
#pragma unroll
        for (int i = 0; i < 16; ++i) pw[i] = src[i];
        pb = bias[pcol];
    };
    if (tid >= 256) loadp(We, be);

    // plain proj dot: static offsets, no extra address VALU (R12-proven)
    auto projdot = [&](const float* hsrc) -> float {
        const float4* hp = (const float4*)(hsrc + kq * 64);
        float pa = 0.f;
#pragma unroll
        for (int i = 0; i < 16; ++i) {
            float4 hv = hp[i];
            pa = fmaf(pw[i].x, hv.x, pa);
            pa = fmaf(pw[i].y, hv.y, pa);
            pa = fmaf(pw[i].z, hv.z, pa);
            pa = fmaf(pw[i].w, hv.w, pa);
        }
        pa += __shfl_xor(pa, 1);
        pa += __shfl_xor(pa, 2);  // 4 k-quarters combined
        return pa + pb;
    };

    if (tid < 64) {  // h(-1) = 0 lives in buffer 1
        ((float4*)hbuf[1])[tid] = make_float4(0.f, 0.f, 0.f, 0.f);
    }
    __syncthreads();

    float c = 0.f, c_saved = 0.f, h_saved = 0.f;

    for (int t = 0; t < 2 * TT; ++t) {
        const int phase = t >> 7;  // 0 = encoder, 1 = decoder
        const int tt = t & 127;
        const float x = x_lds[t];
        const int rb = (t & 1) ^ 1;  // buffer holding h(t-1)

        // ---- phase 1 (all 8 waves): gate-row dot over own 128-wide slice --
        const float4* h4 = ((const float4*)hbuf[rb]) + half * 32;
        float4 a4 = make_float4(0.f, 0.f, 0.f, 0.f);
#pragma unroll
        for (int i = 0; i < 32; ++i) {
            float4 hv = h4[i];
            a4.x = fmaf(w[i].x, hv.x, a4.x);
            a4.y = fmaf(w[i].y, hv.y, a4.y);
            a4.z = fmaf(w[i].z, hv.z, a4.z);
            a4.w = fmaf(w[i].w, hv.w, a4.w);
        }
        float acc = (a4.x + a4.y) + (a4.z + a4.w);
        acc += __shfl_xor(acc, 1);  // combine the two k-halves
        float gv = acc + bias_r + x * wih_r;  // bias/Wih folded off serial path
        if (half == 0) g_lds[row_local] = gv;
        __syncthreads();  // (A) gates visible; hbuf[t&1] free to write

        // ---- phase 2 (wave 0): minimal serial segment ----
        if (tid < 64) {
            float gi = g_lds[tid];
            float gf = g_lds[64 + tid];
            float gg = g_lds[128 + tid];
            float go = g_lds[192 + tid];
            float si = sigmoid_f(gi);
            float sf = sigmoid_f(gf);
            float tg = tanh_f(gg);
            float so = sigmoid_f(go);
            c = sf * c + si * tg;
            float h = so * tanh_f(c);
            const int ug = g * UPB + tid;
            // publish FIRST: the only VMEM op on wave 0's pre-barrier drain
            unsigned long long pkt =
                ((unsigned long long)(unsigned)(t + 1) << 32) | __float_as_uint(h);
            __hip_atomic_store(&mbox[(t & 1) * BB * HH + b * HH + ug], pkt,
                               __ATOMIC_RELAXED, AGENT);
            if (phase == 0 && tt == last) {
                c_saved = c;
                h_saved = h;
                unsigned long long spkt =
                    (1ull << 32) | (unsigned long long)__float_as_uint(h);
                __hip_atomic_store(&hsave[b * HH + ug], spkt, __ATOMIC_RELAXED, AGENT);
            }
            hbuf[t & 1][ug] = (t == TT - 1) ? h_saved : h;
        }

        // ---- phase 3 (waves 1..3): ring poll of partners' tagged h ----
        if (tid >= 64 && tid < 256) {
            const int p = (g + (tid >> 6)) & 3;  // partner slice 1..3 away
            const int lane = tid & 63;
            const int ppu = p * UPB + lane;
            unsigned long long* src;
            unsigned want;
            if (t == TT - 1) {
                src = &hsave[b * HH + ppu];
                want = 1u;
            } else {
                src = &mbox[(t & 1) * BB * HH + b * HH + ppu];
                want = (unsigned)(t + 1);
            }
            unsigned long long pv;
            {
                unsigned long long r0 = AL(src);
                unsigned long long r1 = AL(src);
                unsigned long long r2 = AL(src);
                unsigned long long r3 = AL(src);
                for (;;) {
                    if ((unsigned)(r0 >> 32) == want) { pv = r0; break; }
                    r0 = AL(src);
                    if ((unsigned)(r1 >> 32) == want) { pv = r1; break; }
                    r1 = AL(src);
                    if ((unsigned)(r2 >> 32) == want) { pv = r2; break; }
                    r2 = AL(src);
                    if ((unsigned)(r3 >> 32) == want) { pv = r3; break; }
                    r3 = AL(src);
                }
            }
            hbuf[t & 1][ppu] = __uint_as_float((unsigned)pv);
        }

        // ---- proj (waves 4..7): e2/d2 row t-1, hidden in the poll window --
        if (tid >= 256 && t >= 1) {
            const float* hsrc = (t == TT) ? h_final : hbuf[rb];
            float pv = projdot(hsrc);
            if (kq == 0) {
                if (t <= TT)
                    e2[(b * TT + (t - 1)) * HH + pcol] = pv;
                else
                    d2[(b * TT + (t - 1 - TT)) * HH + pcol] = pv;
            }
        }
        // at the enc boundary, recover full h(TT-1) (tag TT) into h_final
        if (tid >= 256 && t == TT - 1) {
            unsigned long long* src = &mbox[((TT - 1) & 1) * BB * HH + b * HH + s];
            const unsigned want = (unsigned)TT;
            unsigned long long r0 = AL(src);
            unsigned long long r1 = AL(src);
            unsigned long long pv;
            for (;;) {
                if ((unsigned)(r0 >> 32) == want) { pv = r0; break; }
                r0 = AL(src);
                if ((unsigned)(r1 >> 32) == want) { pv = r1; break; }
                r1 = AL(src);
            }
            h_final[s] = __uint_as_float((unsigned)pv);
        }
        if (tid >= 256 && t == TT) loadp(Wd, bd);

        __syncthreads();  // (B) hbuf[t&1] complete for next step

        if (t == TT - 1) {  // encoder -> decoder transition
            loadw(Whh_d, Wih_d, bih_d, bhh_d);
            c = c_saved;
        }
    }

    // ---- post-loop: d2 row TT-1 from h(2TT-1) (tag 2TT) ----
    if (tid >= 256) {
        unsigned long long* src = &mbox[((2 * TT - 1) & 1) * BB * HH + b * HH + s];
        const unsigned want = (unsigned)(2 * TT);
        unsigned long long r0 = AL(src);
        unsigned long long r1 = AL(src);
        unsigned long long pv;
        for (;;) {
            if ((unsigned)(r0 >> 32) == want) { pv = r0; break; }
            r0 = AL(src);
            if ((unsigned)(r1 >> 32) == want) { pv = r1; break; }
            r1 = AL(src);
        }
        h_final[s] = __uint_as_float((unsigned)pv);
    }
    __syncthreads();
    if (tid >= 256) {
        float pv = projdot(h_final);
        if (kq == 0) d2[(b * TT + (TT - 1)) * HH + pcol] = pv;
    }
}

// ---------------------------------------------------------------------------
// Attention scores: p = tanh(e2_j + d2_i) . v  for a 32x32 (i,j) tile.
// grid = 512 = b(32) x it(4) x jt(4); block = 256; 4x i-register-blocked.
// All 256 CUs busy, 2 blocks/CU (proven ~45us tail in R13/R14).
// ---------------------------------------------------------------------------
#define EPAD 260  // float4-aligned LDS row stride
__global__ __launch_bounds__(256) void attn_p_kernel(
    const float* __restrict__ e2, const float* __restrict__ d2,
    const float* __restrict__ vv, float* __restrict__ p_ws) {
    __shared__ float e2c[32][EPAD];
    __shared__ float d2t[32][EPAD];
    __shared__ float v_lds[HH];

    const int blk = blockIdx.x;
    const int b = blk >> 4;
    const int i0 = ((blk >> 2) & 3) * 32;
    const int j0 = (blk & 3) * 32;
    const int tid = threadIdx.x;
    const int jl = tid & 31, ig = tid >> 5;

    if (tid < 64) *(float4*)&v_lds[tid * 4] = ((const float4*)vv)[tid];
    for (int idx = tid; idx < 32 * 64; idx += 256) {
        int r = idx >> 6, q = idx & 63;
        *(float4*)&d2t[r][q * 4] = ((const float4*)(d2 + (b * TT + i0 + r) * HH))[q];
        *(float4*)&e2c[r][q * 4] = ((const float4*)(e2 + (b * TT + j0 + r) * HH))[q];
    }
    __syncthreads();

    float a0 = 0.f, a1 = 0.f, a2 = 0.f, a3 = 0.f;
    for (int h = 0; h < HH; h += 4) {
        float4 ev = *(const float4*)&e2c[jl][h];
        float4 vx = *(const float4*)&v_lds[h];
        float4 d0 = *(const float4*)&d2t[ig * 4 + 0][h];
        float4 d1 = *(const float4*)&d2t[ig * 4 + 1][h];
        float4 d2v = *(const float4*)&d2t[ig * 4 + 2][h];
        float4 d3 = *(const float4*)&d2t[ig * 4 + 3][h];
        a0 = fmaf(tanh_f(ev.x + d0.x), vx.x, a0);
        a0 = fmaf(tanh_f(ev.y + d0.y), vx.y, a0);
        a0 = fmaf(tanh_f(ev.z + d0.z), vx.z, a0);
        a0 = fmaf(tanh_f(ev.w + d0.w), vx.w, a0);
        a1 = fmaf(tanh_f(ev.x + d1.x), vx.x, a1);
        a1 = fmaf(tanh_f(ev.y + d1.y), vx.y, a1);
        a1 = fmaf(tanh_f(ev.z + d1.z), vx.z, a1);
        a1 = fmaf(tanh_f(ev.w + d1.w), vx.w, a1);
        a2 = fmaf(tanh_f(ev.x + d2v.x), vx.x, a2);
        a2 = fmaf(tanh_f(ev.y + d2v.y), vx.y, a2);
        a2 = fmaf(tanh_f(ev.z + d2v.z), vx.z, a2);
        a2 = fmaf(tanh_f(ev.w + d2v.w), vx.w, a2);
        a3 = fmaf(tanh_f(ev.x + d3.x), vx.x, a3);
        a3 = fmaf(tanh_f(ev.y + d3.y), vx.y, a3);
        a3 = fmaf(tanh_f(ev.z + d3.z), vx.z, a3);
        a3 = fmaf(tanh_f(ev.w + d3.w), vx.w, a3);
    }
    float* pr = p_ws + (b * TT + i0 + ig * 4) * TT + j0 + jl;
    pr[0 * TT] = a0;
    pr[1 * TT] = a1;
    pr[2 * TT] = a2;
    pr[3 * TT] = a3;
}

// ---------------------------------------------------------------------------
// Softmax over j with mask (memory-bound finisher).
// grid = 256 = b(32) x 8 row-tiles (16 rows); block = 256 (16 rows x 16 lanes).
// ---------------------------------------------------------------------------
__global__ __launch_bounds__(256) void attn_sm_kernel(
    const float* __restrict__ p_ws, const float* __restrict__ seq,
    float* __restrict__ out) {
    const int blk = blockIdx.x;
    const int b = blk >> 3;
    const int r0 = (blk & 7) * 16;
    const int tid = threadIdx.x;
    const int r = tid >> 4, l16 = tid & 15;
    const int row = (b * TT + r0 + r) * TT;

    float xr[8];
    float m = -1e30f;
#pragma unroll
    for (int k = 0; k < 8; ++k) {
        const int j = l16 + 16 * k;
        float x = p_ws[row + j];
        float sv = (j == 0) ? 0.1f : seq[b * TT + j];
        if (sv == 0.f) x -= 1000.f;
        xr[k] = x;
        m = fmaxf(m, x);
    }
#pragma unroll
    for (int o = 8; o >= 1; o >>= 1) m = fmaxf(m, __shfl_xor(m, o));
    float s = 0.f;
#pragma unroll
    for (int k = 0; k < 8; ++k) {
        xr[k] = __expf(xr[k] - m);
        s += xr[k];
    }
#pragma unroll
    for (int o = 8; o >= 1; o >>= 1) s += __shfl_xor(s, o);
    float inv = rcp_f(s);
#pragma unroll
    for (int k = 0; k < 8; ++k) out[row + l16 + 16 * k] = xr[k] * inv;
}

// ---------------------------------------------------------------------------
extern "C" void kernel_launch(void* const* d_in, const int* in_sizes, int n_in,
                              void* d_out, int out_size, void* d_ws, size_t ws_size,
                              hipStream_t stream) {
    const float* seq = (const float*)d_in[0];
    const int* seq_m = (const int*)d_in[1];
    const float* target = (const float*)d_in[2];
    const float* Wih_e = (const float*)d_in[3];
    const float* Whh_e = (const float*)d_in[4];
    const float* bih_e = (const float*)d_in[5];
    const float* bhh_e = (const float*)d_in[6];
    const float* Wih_d = (const float*)d_in[7];
    const float* Whh_d = (const float*)d_in[8];
    const float* bih_d = (const float*)d_in[9];
    const float* bhh_d = (const float*)d_in[10];
    const float* We = (const float*)d_in[11];
    const float* be = (const float*)d_in[12];
    const float* Wd = (const float*)d_in[13];
    const float* bd = (const float*)d_in[14];
    const float* vv = (const float*)d_in[15];

    float* ws = (float*)d_ws;
    const size_t SZ_ED = (size_t)BB * TT * HH;  // 1,048,576 floats
    float* e2 = ws;
    float* d2 = e2 + SZ_ED;
    float* p_ws = d2 + SZ_ED;                               // [B][128][128]
    unsigned long long* mbox =
        (unsigned long long*)(p_ws + (size_t)BB * TT * TT);  // [2][B][H]
    unsigned long long* hsave = mbox + 2 * BB * HH;          // [B][H]

    const size_t needed = (2 * SZ_ED + (size_t)BB * TT * TT) * sizeof(float) +
                          3 * BB * HH * sizeof(unsigned long long);
    if (ws_size < needed) return;

    hipMemsetAsync(mbox, 0, 3 * BB * HH * sizeof(unsigned long long), stream);
    lstm_kernel<<<BB * G4, 512, 0, stream>>>(seq, seq_m, target, Wih_e, Whh_e, bih_e,
                                             bhh_e, Wih_d, Whh_d, bih_d, bhh_d, We,
                                             be, Wd, bd, e2, d2, mbox, hsave);
    attn_p_kernel<<<512, 256, 0, stream>>>(e2, d2, vv, p_ws);
    attn_sm_kernel<<<256, 256, 0, stream>>>(p_ws, seq, (float*)d_out);
}